// Round 13
// baseline (152.776 us; speedup 1.0000x reference)
//
#include <hip/hip_runtime.h>

// ---------------------------------------------------------------------------
// Violin Attention: x->QKV GEMM -> masked softmax attention -> proj GEMM
// B=16 N=577 C=768 H=12 D=64 NC=8 P=576. f32 in/out, fp16 MFMA internally.
// ---------------------------------------------------------------------------

typedef _Float16 f16;
typedef _Float16 half8 __attribute__((ext_vector_type(8)));
typedef _Float16 half4 __attribute__((ext_vector_type(4)));
typedef float floatx4 __attribute__((ext_vector_type(4)));

#define DEVINL __device__ __forceinline__

#define Bb 16
#define NN 577
#define CC 768
#define HH 12
#define DD 64
#define MM (Bb * NN)   // 9232
#define VTLD 584       // padded row stride for V^T (16B-aligned rows)
#define MLD 580        // padded mask row stride (16B-aligned rows)
#define CLD 136        // padded LDS row stride for q/k epilogue bounce (f16)
#define TLD 264        // padded LDS row stride for v epilogue bounce (f16)
#define BUFS 24576     // f16 per GEMM LDS buffer (A 16384 + B 8192 = 48KB)

// async global->LDS, 16B per lane; LDS dest must be wave-uniform-base + lane*16
DEVINL void async_copy16(void* lds, const void* g) {
  __builtin_amdgcn_global_load_lds(
      (const __attribute__((address_space(1))) void*)g,
      (__attribute__((address_space(3))) void*)lds, 16, 0, 0);
}

// swizzled b128 read from an LDS tile with 64-f16 (128B) rows.
// 16B chunk c of row r lives at position c ^ (r&7)  (involution; matches staging)
DEVINL half8 ld_swz(const f16* lds, int row, int chunk) {
  return *(const half8*)(lds + row * 64 + ((chunk ^ (row & 7)) << 3));
}

// T1: bijective XCD-aware block swizzle (m204). orig -> wgid such that each
// XCD (orig%8) owns a contiguous wgid chunk.
DEVINL int xcd_swizzle(int orig, int nwg) {
  int q = nwg >> 3, r = nwg & 7;
  int xcd = orig & 7, loc = orig >> 3;
  return (xcd < r ? xcd * (q + 1) : r * (q + 1) + (xcd - r) * q) + loc;
}

// ---------------------------------------------------------------------------
// merged prep kernel: [0,6924) f32->f16 cvt of x; [6924,8652) qkvw transpose;
// [8652,9228) pw transpose; [9228,16152) mask build. All 256-thread blocks.
// ---------------------------------------------------------------------------
__global__ __launch_bounds__(256)
void prep_kernel(const float* __restrict__ x, const float* __restrict__ qkvw,
                 const float* __restrict__ pw, const float* __restrict__ ai,
                 const float* __restrict__ mw, const float* __restrict__ nrm,
                 const int* __restrict__ ci, f16* __restrict__ x_h,
                 f16* __restrict__ w_t, f16* __restrict__ pw_t,
                 float* __restrict__ Mb) {
  __shared__ float shm[32 * 33];
  const int bid = blockIdx.x;
  const int tid = threadIdx.x;
  if (bid < 6924) {
    // cvt: 6924*256*4 == MM*CC exactly
    int i = (bid * 256 + tid) * 4;
    float4 v = *(const float4*)(x + i);
    half4 o = {(f16)v.x, (f16)v.y, (f16)v.z, (f16)v.w};
    *(half4*)(x_h + i) = o;
  } else if (bid < 9228) {
    // transpose+cvt: [K=768][N3] f32 -> [N3][768] f16 via 32x32 LDS tile
    bool isq = bid < 8652;
    int b2 = bid - (isq ? 6924 : 8652);
    int N3 = isq ? 3 * CC : CC;
    const float* in = isq ? qkvw : pw;
    f16* out = isq ? w_t : pw_t;
    const int k0 = (b2 % 24) * 32, n0 = (b2 / 24) * 32;
    const int tx = tid & 31, ty = tid >> 5;
#pragma unroll
    for (int p = 0; p < 4; ++p)
      shm[(ty + p * 8) * 33 + tx] = in[(size_t)(k0 + ty + p * 8) * N3 + n0 + tx];
    __syncthreads();
#pragma unroll
    for (int p = 0; p < 4; ++p)
      out[(size_t)(n0 + ty + p * 8) * CC + k0 + tx] = (f16)shm[tx * 33 + ty + p * 8];
  } else {
    // mask: M'[h][i][j] = log2e*nrm[h]*sum_c w_c*a_{c,h}^|ci_i-ci_j|, stride MLD
    int b4 = bid - 9228;
    int i = b4 % NN, h = b4 / NN;
    float* la_s = shm; float* wv_s = shm + 8; float* cif = shm + 16;
    float* swn_s = shm + 24;
    if (tid < 8) {
      float av = ai[tid * 12 + h];
      float a = 1.f / (1.f + __expf(-av));
      la_s[tid] = __logf(a);
      wv_s[tid] = mw[tid];
      cif[tid] = (i > 0) ? (float)ci[tid * 576 + (i - 1)] : 0.f;
    }
    if (tid == 0) {
      float s = 0.f;
      for (int c = 0; c < 8; ++c) s += mw[c];
      swn_s[0] = s * nrm[h] * 1.44269504088896f;
    }
    __syncthreads();
    const float nr = nrm[h] * 1.44269504088896f;
    float* row = Mb + ((size_t)h * NN + i) * MLD;
    for (int j = tid; j < NN; j += 256) {
      float val;
      if (i == 0 || j == 0) {
        val = swn_s[0];
      } else {
        float acc = 0.f;
#pragma unroll
        for (int c = 0; c < 8; ++c) {
          float d = fabsf(cif[c] - (float)ci[c * 576 + (j - 1)]);
          acc += wv_s[c] * __expf(la_s[c] * d);
        }
        val = acc * nr;
      }
      row[j] = val;
    }
  }
}

// ---------------------------------------------------------------------------
// 256x128x768 GEMM mainloop, PHASE-INTERLEAVED (T3+T4+T5 port of the 8-phase
// template). 512 threads (8 waves 4x2, each 64x64). BK=64, 12 K-steps.
// 3 LDS buffers (144KB), 2-deep prefetch: stage(t+2) issued during step t.
// Per K-step, 2 phases (kk=0 / kk=1), each:
//   { 8 x ds_read_b128 (current buf) || 3 x global_load_lds (buf t+2) }
//   -> s_barrier -> lgkmcnt(0)+sched_barrier -> setprio(1) 16 MFMA setprio(0)
//   -> s_barrier.
// vmcnt(6) once per K-step (in phase B, before its barrier): retires exactly
// stage(t+1), keeps stage(t+2)'s 6 loads in flight -- never drains to 0 in
// the main loop (only the t=10 boundary, where no further stage exists).
// Rationale: r12 measured 605 TF == m233's 607 TF 2-phase ceiling; the
// phase-interleave + counted-vmcnt-across-barriers is the documented escape.
// ---------------------------------------------------------------------------
DEVINL void gemm_mainloop(const f16* __restrict__ A, const f16* __restrict__ Bt,
                          int arow0, int brow0, int maxar,
                          f16* SMEM, floatx4 acc[4][4], int tid) {
  const int lane = tid & 63;
  const int wid = tid >> 6;            // 0..7
  const int wr = wid >> 1, wc = wid & 1;
  const int l15 = lane & 15, g = lane >> 4;
  const int r_ = tid >> 3, cp_ = tid & 7;        // r_ 0..63
  const int lc_ = (cp_ ^ (r_ & 7)) << 3;   // pre-swizzled global col offset

  // stage split: phase A issues A-rows q=0..2 (3 loads); phase B issues
  // A-row q=3 + B-rows q=0..1 (3 loads). 6 gload_lds per thread per K-step.
  auto stageA3 = [&](f16* As, int k0) {
#pragma unroll
    for (int q = 0; q < 3; ++q) {
      int r = q * 64 + r_;
      int ar = arow0 + r; if (ar > maxar) ar = maxar;
      async_copy16(As + (q * 512 + tid) * 8, A + (size_t)ar * CC + k0 + lc_);
    }
  };
  auto stageRest = [&](f16* As, f16* Bs, int k0) {
    {
      int r = 192 + r_;
      int ar = arow0 + r; if (ar > maxar) ar = maxar;
      async_copy16(As + (3 * 512 + tid) * 8, A + (size_t)ar * CC + k0 + lc_);
    }
#pragma unroll
    for (int q = 0; q < 2; ++q) {
      int r = q * 64 + r_;
      async_copy16(Bs + (q * 512 + tid) * 8, Bt + (size_t)(brow0 + r) * CC + k0 + lc_);
    }
  };

  const int nt = CC / 64;  // 12
  // prologue: stage(0), stage(1); retire stage(0), keep stage(1) in flight
  stageA3(SMEM, 0);
  stageRest(SMEM, SMEM + 16384, 0);
  stageA3(SMEM + BUFS, 64);
  stageRest(SMEM + BUFS, SMEM + BUFS + 16384, 64);
  asm volatile("s_waitcnt vmcnt(6)" ::: "memory");
  __builtin_amdgcn_s_barrier();

#pragma unroll 1
  for (int t = 0; t < nt; ++t) {
    f16* cAs = SMEM + (t % 3) * BUFS;
    f16* cBs = cAs + 16384;
    f16* nAs = SMEM + ((t + 2) % 3) * BUFS;
    f16* nBs = nAs + 16384;
    const bool more = (t + 2 < nt);
    // ---- phase A (kk=0) ----
    half8 af[4], bf[4];
#pragma unroll
    for (int mi = 0; mi < 4; ++mi) af[mi] = ld_swz(cAs, wr * 64 + mi * 16 + l15, g);
#pragma unroll
    for (int ni = 0; ni < 4; ++ni) bf[ni] = ld_swz(cBs, wc * 64 + ni * 16 + l15, g);
    if (more) stageA3(nAs, (t + 2) * 64);
    __builtin_amdgcn_s_barrier();
    asm volatile("s_waitcnt lgkmcnt(0)" ::: "memory");
    __builtin_amdgcn_sched_barrier(0);
    __builtin_amdgcn_s_setprio(1);
#pragma unroll
    for (int mi = 0; mi < 4; ++mi)
#pragma unroll
      for (int ni = 0; ni < 4; ++ni)
        acc[mi][ni] = __builtin_amdgcn_mfma_f32_16x16x32_f16(af[mi], bf[ni], acc[mi][ni], 0, 0, 0);
    __builtin_amdgcn_s_setprio(0);
    __builtin_amdgcn_s_barrier();
    // ---- phase B (kk=1) ----
#pragma unroll
    for (int mi = 0; mi < 4; ++mi) af[mi] = ld_swz(cAs, wr * 64 + mi * 16 + l15, 4 + g);
#pragma unroll
    for (int ni = 0; ni < 4; ++ni) bf[ni] = ld_swz(cBs, wc * 64 + ni * 16 + l15, 4 + g);
    if (more) {
      stageRest(nAs, nBs, (t + 2) * 64);
      asm volatile("s_waitcnt vmcnt(6)" ::: "memory");
    } else if (t + 1 < nt) {
      asm volatile("s_waitcnt vmcnt(0)" ::: "memory");
    }
    __builtin_amdgcn_s_barrier();
    asm volatile("s_waitcnt lgkmcnt(0)" ::: "memory");
    __builtin_amdgcn_sched_barrier(0);
    __builtin_amdgcn_s_setprio(1);
#pragma unroll
    for (int mi = 0; mi < 4; ++mi)
#pragma unroll
      for (int ni = 0; ni < 4; ++ni)
        acc[mi][ni] = __builtin_amdgcn_mfma_f32_16x16x32_f16(af[mi], bf[ni], acc[mi][ni], 0, 0, 0);
    __builtin_amdgcn_s_setprio(0);
    __builtin_amdgcn_s_barrier();
  }
}

// QKV GEMM: x_h [9232][768] * w_t [2304][768]^T -> q,k [B,H,N,D], v^T [B,H,D,VTLD]
// 256x128 tile; epilogue: acc -> LDS bounce (padded) -> coalesced half8 stores.
__global__ __launch_bounds__(512, 2)
void gemm_qkv(const f16* __restrict__ A, const f16* __restrict__ Bt,
              f16* __restrict__ qb, f16* __restrict__ kb, f16* __restrict__ vt) {
  __shared__ __align__(16) f16 SMEM[3 * BUFS];   // 144 KB, 3 dbuf; epilogue aliases
  floatx4 acc[4][4] = {};
  const int nwg = 18 * 37;
  const int wgid = xcd_swizzle(blockIdx.y * gridDim.x + blockIdx.x, nwg);
  const int m0 = (wgid / 18) * 256, n0 = (wgid % 18) * 128;
  gemm_mainloop(A, Bt, m0, n0, MM - 1, SMEM, acc, threadIdx.x);
  const int tid = threadIdx.x, lane = tid & 63, wid = tid >> 6;
  const int wr = wid >> 1, wc = wid & 1, l15 = lane & 15, g = lane >> 4;
  const int t = n0 / CC;                 // 0=q, 1=k, 2=v (uniform per block)
  const int h0 = (n0 - t * CC) >> 6;
  // (mainloop ended with s_barrier; SMEM free to reuse)
  if (t < 2) {
    // SMEM[m][n3], m 0..255, stride CLD (34816 f16 <= 3*BUFS)
#pragma unroll
    for (int mi = 0; mi < 4; ++mi)
#pragma unroll
      for (int ni = 0; ni < 4; ++ni)
#pragma unroll
        for (int r = 0; r < 4; ++r)
          SMEM[(wr * 64 + mi * 16 + 4 * g + r) * CLD + wc * 64 + ni * 16 + l15] =
              (f16)acc[mi][ni][r];
    __syncthreads();
    f16* dst = (t == 0) ? qb : kb;
#pragma unroll
    for (int p = 0; p < 8; ++p) {
      int c = p * 512 + tid;             // 4096 chunks of 8 f16
      int ml = c >> 4, n3c = (c & 15) << 3;
      int mg = m0 + ml;
      if (mg < MM) {
        int b = mg / NN, n = mg - b * NN;
        int h = h0 + (n3c >> 6), d0 = n3c & 63;
        half8 v = *(const half8*)(SMEM + ml * CLD + n3c);
        *(half8*)(dst + ((size_t)(b * HH + h) * NN + n) * DD + d0) = v;
      }
    }
  } else {
    // SMEM[n3][m] transposed, n3 0..127, stride TLD (33792 f16 <= 3*BUFS)
#pragma unroll
    for (int mi = 0; mi < 4; ++mi)
#pragma unroll
      for (int ni = 0; ni < 4; ++ni)
#pragma unroll
        for (int r = 0; r < 4; ++r)
          SMEM[(wc * 64 + ni * 16 + l15) * TLD + wr * 64 + mi * 16 + 4 * g + r] =
              (f16)acc[mi][ni][r];
    __syncthreads();
#pragma unroll
    for (int p = 0; p < 8; ++p) {
      int c = p * 512 + tid;             // 128 n3 x 32 m-chunks = 4096
      int n3 = c >> 5, mc = (c & 31) << 3;
      int mg = m0 + mc;
      int h = h0 + (n3 >> 6), d = n3 & 63;
      half8 v = *(const half8*)(SMEM + n3 * TLD + mc);
      int b0 = mg / NN;
      if (mg + 7 < MM && (mg + 7) / NN == b0) {
        *(half8*)(vt + ((size_t)(b0 * HH + h) * DD + d) * VTLD + (mg - b0 * NN)) = v;
      } else {
#pragma unroll
        for (int e = 0; e < 8; ++e) {
          int m2 = mg + e;
          if (m2 < MM) {
            int b = m2 / NN;
            vt[((size_t)(b * HH + h) * DD + d) * VTLD + (m2 - b * NN)] = v[e];
          }
        }
      }
    }
  }
}

// Proj GEMM: aout [9232][768] * pw_t [768][768]^T + bias -> out f32
__global__ __launch_bounds__(512, 2)
void gemm_proj(const f16* __restrict__ A, const f16* __restrict__ Bt,
               const float* __restrict__ bias, float* __restrict__ out) {
  __shared__ __align__(16) f16 SMEM[3 * BUFS];
  floatx4 acc[4][4] = {};
  const int nwg = 6 * 37;
  const int wgid = xcd_swizzle(blockIdx.y * gridDim.x + blockIdx.x, nwg);
  const int m0 = (wgid / 6) * 256, n0 = (wgid % 6) * 128;
  gemm_mainloop(A, Bt, m0, n0, MM - 1, SMEM, acc, threadIdx.x);
  const int lane = threadIdx.x & 63, wid = threadIdx.x >> 6;
  const int wr = wid >> 1, wc = wid & 1, l15 = lane & 15, g = lane >> 4;
#pragma unroll
  for (int mi = 0; mi < 4; ++mi)
#pragma unroll
    for (int ni = 0; ni < 4; ++ni)
#pragma unroll
      for (int r = 0; r < 4; ++r) {
        int m = m0 + wr * 64 + mi * 16 + 4 * g + r;
        if (m >= MM) continue;
        int n = n0 + wc * 64 + ni * 16 + l15;
        out[(size_t)m * CC + n] = acc[mi][ni][r] + bias[n];
      }
}

// ---------------------------------------------------------------------------
// Flash attention, swapped-operand form, counted-vmcnt pipeline.
// grid=960 blocks remapped so each XCD owns a contiguous (h-major) chunk.
// 8 waves x 16 q-rows (512 threads), 2 blocks/CU -> 4 waves/SIMD resident
// while the per-CU (b,h) window stays at 2 (L2-safe; r6 showed 3 thrashes).
// S^T = mfma16x16x32(K,Q): lane holds S[q=l15][j=4g+r] == B-frag of 16x16x16
// -> PV with zero P movement. Defer-rescale (T13) with __any-gated local-max
// test, tree max, hoisted tail. V path = r10 form (r11's interleaved-V
// halved bank conflicts but 4x'd V-stage VMEM ops: 55.5->62us, reverted).
// VMEM per tile: [mask(t+1): 4][stage(t+1): 2] -> vmcnt(4) retires exactly
// mask(t)+stage(t), each covered by a full tile of compute.
// ---------------------------------------------------------------------------
__global__ __launch_bounds__(512, 4)
void attn_kernel(const f16* __restrict__ qb, const f16* __restrict__ kb,
                 const f16* __restrict__ vt, const float* __restrict__ Mb,
                 f16* __restrict__ aout) {
  __shared__ f16 Ks[2][64 * 64];   // [j][d] swizzled
  __shared__ f16 Vs[2][64 * 64];   // [d][j] swizzled
  const int D0 = (blockIdx.z * gridDim.y + blockIdx.y) * gridDim.x + blockIdx.x;
  const int wgid = xcd_swizzle(D0, 5 * HH * Bb);   // 960 % 8 == 0
  const int it = wgid % 5;
  const int rem = wgid / 5;
  const int b = rem % Bb, h = rem / Bb;
  const int tid = threadIdx.x, lane = tid & 63, wid = tid >> 6;  // wid 0..7
  const int l15 = lane & 15, g = lane >> 4;
  const size_t bh = (size_t)b * HH + h;
  const f16* qbh = qb + bh * NN * DD;
  const f16* kbh = kb + bh * NN * DD;
  const f16* vbh = vt + bh * DD * VTLD;
  const float* Mh = Mb + (size_t)h * NN * MLD;
  const int row0w = it * 128 + wid * 16;

  // Q B-fragments (held whole kernel): lane holds Q[q=l15][kk*32+g*8 ..+8]
  half8 qB0, qB1;
  {
    int qr = row0w + l15; if (qr > NN - 1) qr = NN - 1;
    const f16* qp = qbh + (size_t)qr * DD + g * 8;
    qB0 = *(const half8*)qp;
    qB1 = *(const half8*)(qp + 32);
  }
  // clamped mask row base
  const float* Mrow;
  {
    int r0 = row0w + l15; if (r0 > NN - 1) r0 = NN - 1;
    Mrow = Mh + (size_t)r0 * MLD + 4 * g;
  }

  floatx4 acc[4] = {};                    // O^T: lane holds O[q=l15][d=dt*16+4g+r]
  float lsum = 0.f;
  float mrun = -3e38f;

  // 512 threads stage a full 64x64 tile in one pass: tid = row*8 + chunk
  const int sr_ = tid >> 3, scp_ = tid & 7;
  const int slc_ = (scp_ ^ (sr_ & 7)) << 3;   // pre-swizzled global col offset
  auto stage = [&](f16* Kd, f16* Vd, int j0) {
    int j = j0 + sr_; if (j > NN - 1) j = NN - 1;
    async_copy16(Kd + tid * 8, kbh + (size_t)j * DD + slc_);
    async_copy16(Vd + tid * 8, vbh + (size_t)sr_ * VTLD + j0 + slc_);
  };
  auto ldmask = [&](floatx4 m4[4], int j0) {
#pragma unroll
    for (int jt = 0; jt < 4; ++jt)
      m4[jt] = *(const floatx4*)(Mrow + j0 + jt * 16);
  };
  auto compute = [&](const f16* Kc, const f16* Vc, floatx4 m4[4], int j0) {
    // S^T = K Q^T : sf[jt][r] = S[q=l15][j0 + jt*16 + 4g + r]
    floatx4 sf[4];
#pragma unroll
    for (int jt = 0; jt < 4; ++jt) {
      half8 ka0 = ld_swz(Kc, jt * 16 + l15, g);
      half8 ka1 = ld_swz(Kc, jt * 16 + l15, 4 + g);
      floatx4 z = {0.f, 0.f, 0.f, 0.f};
      z = __builtin_amdgcn_mfma_f32_16x16x32_f16(ka0, qB0, z, 0, 0, 0);
      z = __builtin_amdgcn_mfma_f32_16x16x32_f16(ka1, qB1, z, 0, 0, 0);
      sf[jt] = z;
    }
    // apply mask
#pragma unroll
    for (int jt = 0; jt < 4; ++jt)
#pragma unroll
      for (int r = 0; r < 4; ++r) sf[jt][r] *= m4[jt][r];
    // tail columns -> -inf (wave-uniform branch; taken only on last tile)
    if (j0 + 64 > NN) {
#pragma unroll
      for (int jt = 0; jt < 4; ++jt)
#pragma unroll
        for (int r = 0; r < 4; ++r)
          if (j0 + jt * 16 + 4 * g + r >= NN) sf[jt][r] = -3e38f;
    }
    // balanced-tree local max; cross-lane reduce+rescale only when needed
    float pj[4];
#pragma unroll
    for (int jt = 0; jt < 4; ++jt)
      pj[jt] = fmaxf(fmaxf(sf[jt][0], sf[jt][1]), fmaxf(sf[jt][2], sf[jt][3]));
    float pmax_loc = fmaxf(fmaxf(pj[0], pj[1]), fmaxf(pj[2], pj[3]));
    if (__any(pmax_loc - mrun > 8.f)) {
      float pmax = fmaxf(pmax_loc, __shfl_xor(pmax_loc, 16));
      pmax = fmaxf(pmax, __shfl_xor(pmax, 32));
      float mnew = fmaxf(mrun, pmax);
      float fac = __builtin_amdgcn_exp2f(mrun - mnew);
      mrun = mnew;
      lsum *= fac;
#pragma unroll
      for (int dt = 0; dt < 4; ++dt)
#pragma unroll
        for (int r = 0; r < 4; ++r) acc[dt][r] *= fac;
    }
    half4 pB[4];
    float lsj[4];
#pragma unroll
    for (int jt = 0; jt < 4; ++jt) {
      half4 pb;
      float p0 = __builtin_amdgcn_exp2f(sf[jt][0] - mrun);
      float p1 = __builtin_amdgcn_exp2f(sf[jt][1] - mrun);
      float p2 = __builtin_amdgcn_exp2f(sf[jt][2] - mrun);
      float p3 = __builtin_amdgcn_exp2f(sf[jt][3] - mrun);
      pb[0] = (f16)p0; pb[1] = (f16)p1; pb[2] = (f16)p2; pb[3] = (f16)p3;
      lsj[jt] = (p0 + p1) + (p2 + p3);
      pB[jt] = pb;
    }
    lsum += (lsj[0] + lsj[1]) + (lsj[2] + lsj[3]);
    // O^T += V^T P^T  (16x16x16: A-frag k=(l>>4)*4+e matches lane-local P)
#pragma unroll
    for (int dt = 0; dt < 4; ++dt)
#pragma unroll
      for (int jt = 0; jt < 4; ++jt) {
        int c16 = (jt * 2 + (g >> 1)) ^ (l15 & 7);   // swizzled 16B chunk
        half4 va = *(const half4*)(Vc + (dt * 16 + l15) * 64 + (c16 << 3) + (g & 1) * 4);
        acc[dt] = __builtin_amdgcn_mfma_f32_16x16x16f16(va, pB[jt], acc[dt], 0, 0, 0);
      }
  };

  floatx4 m4A[4], m4B[4];
  stage(Ks[0], Vs[0], 0);   // 2 global_load_lds
  ldmask(m4A, 0);           // 4 loads

  // 10 tiles, hand-unrolled x2 (even tile -> buf0/m4A, odd tile -> buf1/m4B)
#pragma unroll 1
  for (int t = 0; t < 10; t += 2) {
    // ---- even tile t ----
    ldmask(m4B, (t + 1) * 64);
    asm volatile("s_waitcnt vmcnt(4)" ::: "memory");
    __builtin_amdgcn_s_barrier();
    __builtin_amdgcn_sched_barrier(0);
    stage(Ks[1], Vs[1], (t + 1) * 64);
    compute(Ks[0], Vs[0], m4A, t * 64);
    // ---- odd tile t+1 ----
    const int j2 = (t + 2 < 10) ? (t + 2) * 64 : 0;   // dummy reload on tail
    ldmask(m4A, j2);
    asm volatile("s_waitcnt vmcnt(4)" ::: "memory");
    __builtin_amdgcn_s_barrier();
    __builtin_amdgcn_sched_barrier(0);
    stage(Ks[0], Vs[0], j2);
    compute(Ks[1], Vs[1], m4B, (t + 1) * 64);
  }

  // epilogue: reduce lsum across g-groups, normalize, store [b][n][h][d] f16
  {
    float v = lsum;
    v += __shfl_xor(v, 16);
    v += __shfl_xor(v, 32);
    float linv = 1.f / v;
    int n = row0w + l15;
    if (n < NN) {
#pragma unroll
      for (int dt = 0; dt < 4; ++dt) {
        half4 o;
#pragma unroll
        for (int r = 0; r < 4; ++r) o[r] = (f16)(acc[dt][r] * linv);
        *(half4*)(aout + ((size_t)(b * NN + n)) * CC + h * DD + dt * 16 + 4 * g) = o;
      }
    }
  }
}

// ---------------------------------------------------------------------------
extern "C" void kernel_launch(void* const* d_in, const int* in_sizes, int n_in,
                              void* d_out, int out_size, void* d_ws, size_t ws_size,
                              hipStream_t stream) {
  const float* x    = (const float*)d_in[0];
  const float* qkvw = (const float*)d_in[1];
  const float* pw   = (const float*)d_in[2];
  const float* pb   = (const float*)d_in[3];
  const float* ai   = (const float*)d_in[4];
  const float* mw   = (const float*)d_in[5];
  const float* nrm  = (const float*)d_in[6];
  const int*   ci   = (const int*)d_in[7];
  float* out = (float*)d_out;

  char* wsb = (char*)d_ws;
  size_t off = 0;
  auto alloc = [&](size_t bytes) {
    char* p = wsb + off;
    off += (bytes + 255) & ~(size_t)255;
    return p;
  };
  f16*   x_h  = (f16*)alloc((size_t)MM * CC * 2);        // also reused as aout
  f16*   w_t  = (f16*)alloc((size_t)3 * CC * CC * 2);
  f16*   pw_t = (f16*)alloc((size_t)CC * CC * 2);
  float* Mb   = (float*)alloc((size_t)HH * NN * MLD * 4 + 1024);
  f16*   qb   = (f16*)alloc((size_t)Bb * HH * NN * DD * 2);
  f16*   kb   = (f16*)alloc((size_t)Bb * HH * NN * DD * 2);
  f16*   vt   = (f16*)alloc((size_t)Bb * HH * DD * VTLD * 2);
  (void)alloc(4096);  // tail pad: V^T tail-tile staging reads a few chunks past end
  f16* aout = x_h;    // x_h dead after gemm_qkv; alias to save workspace

  prep_kernel<<<16152, 256, 0, stream>>>(x, qkvw, pw, ai, mw, nrm, ci,
                                         x_h, w_t, pw_t, Mb);
  gemm_qkv<<<dim3(18, 37), 512, 0, stream>>>(x_h, w_t, qb, kb, vt);
  attn_kernel<<<dim3(5, HH, Bb), 512, 0, stream>>>(qb, kb, vt, Mb, aout);
  gemm_proj<<<dim3(6, 37), 512, 0, stream>>>(aout, pw_t, pb, out);
}

// Round 14
// 148.214 us; speedup vs baseline: 1.0308x; 1.0308x over previous
//
#include <hip/hip_runtime.h>

// ---------------------------------------------------------------------------
// Violin Attention: x->QKV GEMM -> masked softmax attention -> proj GEMM
// B=16 N=577 C=768 H=12 D=64 NC=8 P=576. f32 in/out, fp16 MFMA internally.
// r14 = clean revert to r12 (best: 148.6us). r13's phase-interleave refuted:
// at 64x64/wave the phases are 16 MFMA vs 8 ds_reads + 2 extra barriers/step
// (barrier quantization); 256^2 tile refuted by grid-tail arithmetic
// (333 blocks @1/CU -> 2 waves of 2x-work blocks ~ 64us > 54us).
// ---------------------------------------------------------------------------

typedef _Float16 f16;
typedef _Float16 half8 __attribute__((ext_vector_type(8)));
typedef _Float16 half4 __attribute__((ext_vector_type(4)));
typedef float floatx4 __attribute__((ext_vector_type(4)));

#define DEVINL __device__ __forceinline__

#define Bb 16
#define NN 577
#define CC 768
#define HH 12
#define DD 64
#define MM (Bb * NN)   // 9232
#define VTLD 584       // padded row stride for V^T (16B-aligned rows)
#define MLD 580        // padded mask row stride (16B-aligned rows)
#define CLD 136        // padded LDS row stride for q/k epilogue bounce (f16)
#define TLD 264        // padded LDS row stride for v epilogue bounce (f16)

// async global->LDS, 16B per lane; LDS dest must be wave-uniform-base + lane*16
DEVINL void async_copy16(void* lds, const void* g) {
  __builtin_amdgcn_global_load_lds(
      (const __attribute__((address_space(1))) void*)g,
      (__attribute__((address_space(3))) void*)lds, 16, 0, 0);
}

// swizzled b128 read from an LDS tile with 64-f16 (128B) rows.
// 16B chunk c of row r lives at position c ^ (r&7)  (involution; matches staging)
DEVINL half8 ld_swz(const f16* lds, int row, int chunk) {
  return *(const half8*)(lds + row * 64 + ((chunk ^ (row & 7)) << 3));
}

// T1: bijective XCD-aware block swizzle (m204). orig -> wgid such that each
// XCD (orig%8) owns a contiguous wgid chunk.
DEVINL int xcd_swizzle(int orig, int nwg) {
  int q = nwg >> 3, r = nwg & 7;
  int xcd = orig & 7, loc = orig >> 3;
  return (xcd < r ? xcd * (q + 1) : r * (q + 1) + (xcd - r) * q) + loc;
}

// ---------------------------------------------------------------------------
// merged prep kernel: [0,6924) f32->f16 cvt of x; [6924,8652) qkvw transpose;
// [8652,9228) pw transpose; [9228,16152) mask build. All 256-thread blocks.
// ---------------------------------------------------------------------------
__global__ __launch_bounds__(256)
void prep_kernel(const float* __restrict__ x, const float* __restrict__ qkvw,
                 const float* __restrict__ pw, const float* __restrict__ ai,
                 const float* __restrict__ mw, const float* __restrict__ nrm,
                 const int* __restrict__ ci, f16* __restrict__ x_h,
                 f16* __restrict__ w_t, f16* __restrict__ pw_t,
                 float* __restrict__ Mb) {
  __shared__ float shm[32 * 33];
  const int bid = blockIdx.x;
  const int tid = threadIdx.x;
  if (bid < 6924) {
    // cvt: 6924*256*4 == MM*CC exactly
    int i = (bid * 256 + tid) * 4;
    float4 v = *(const float4*)(x + i);
    half4 o = {(f16)v.x, (f16)v.y, (f16)v.z, (f16)v.w};
    *(half4*)(x_h + i) = o;
  } else if (bid < 9228) {
    // transpose+cvt: [K=768][N3] f32 -> [N3][768] f16 via 32x32 LDS tile
    bool isq = bid < 8652;
    int b2 = bid - (isq ? 6924 : 8652);
    int N3 = isq ? 3 * CC : CC;
    const float* in = isq ? qkvw : pw;
    f16* out = isq ? w_t : pw_t;
    const int k0 = (b2 % 24) * 32, n0 = (b2 / 24) * 32;
    const int tx = tid & 31, ty = tid >> 5;
#pragma unroll
    for (int p = 0; p < 4; ++p)
      shm[(ty + p * 8) * 33 + tx] = in[(size_t)(k0 + ty + p * 8) * N3 + n0 + tx];
    __syncthreads();
#pragma unroll
    for (int p = 0; p < 4; ++p)
      out[(size_t)(n0 + ty + p * 8) * CC + k0 + tx] = (f16)shm[tx * 33 + ty + p * 8];
  } else {
    // mask: M'[h][i][j] = log2e*nrm[h]*sum_c w_c*a_{c,h}^|ci_i-ci_j|, stride MLD
    int b4 = bid - 9228;
    int i = b4 % NN, h = b4 / NN;
    float* la_s = shm; float* wv_s = shm + 8; float* cif = shm + 16;
    float* swn_s = shm + 24;
    if (tid < 8) {
      float av = ai[tid * 12 + h];
      float a = 1.f / (1.f + __expf(-av));
      la_s[tid] = __logf(a);
      wv_s[tid] = mw[tid];
      cif[tid] = (i > 0) ? (float)ci[tid * 576 + (i - 1)] : 0.f;
    }
    if (tid == 0) {
      float s = 0.f;
      for (int c = 0; c < 8; ++c) s += mw[c];
      swn_s[0] = s * nrm[h] * 1.44269504088896f;
    }
    __syncthreads();
    const float nr = nrm[h] * 1.44269504088896f;
    float* row = Mb + ((size_t)h * NN + i) * MLD;
    for (int j = tid; j < NN; j += 256) {
      float val;
      if (i == 0 || j == 0) {
        val = swn_s[0];
      } else {
        float acc = 0.f;
#pragma unroll
        for (int c = 0; c < 8; ++c) {
          float d = fabsf(cif[c] - (float)ci[c * 576 + (j - 1)]);
          acc += wv_s[c] * __expf(la_s[c] * d);
        }
        val = acc * nr;
      }
      row[j] = val;
    }
  }
}

// ---------------------------------------------------------------------------
// shared 256x128x768 GEMM mainloop, 512 threads (8 waves in 4x2, each 64x64),
// double-buffered LDS + counted vmcnt. A row-major [M][768], Bt [N][768].
// BK=64, 12 K-steps. Per step: stage(t+1) [6 loads/thread] -> vmcnt(6)
// (retires stage(t), keeps stage(t+1) in flight) -> s_barrier -> compute(t)
// -> s_barrier. 96 KB LDS -> 1 block/CU, 2 waves/SIMD; per-wave 64x64 tile
// = 0.5 ds_read per MFMA. Measured 605 TF == m233's 607 TF 2-phase ceiling;
// r13's phase-split regressed (barrier quantization at this tile geometry).
// SMEM (f16 offsets): As0 [0,16K) Bs0 [16K,24K) As1 [24K,40K) Bs1 [40K,48K)
// ---------------------------------------------------------------------------
DEVINL void gemm_mainloop(const f16* __restrict__ A, const f16* __restrict__ Bt,
                          int arow0, int brow0, int maxar,
                          f16* SMEM, floatx4 acc[4][4], int tid) {
  const int lane = tid & 63;
  const int wid = tid >> 6;            // 0..7
  const int wr = wid >> 1, wc = wid & 1;
  const int l15 = lane & 15, g = lane >> 4;
  const int r_ = tid >> 3, cp_ = tid & 7;        // r_ 0..63
  const int lc_ = (cp_ ^ (r_ & 7)) << 3;   // pre-swizzled global col offset

  auto stage = [&](f16* As, f16* Bs, int k0) {
#pragma unroll
    for (int q = 0; q < 4; ++q) {      // A: 256 rows x 8 chunks = 2048
      int r = q * 64 + r_;
      int ar = arow0 + r; if (ar > maxar) ar = maxar;
      async_copy16(As + (q * 512 + tid) * 8, A + (size_t)ar * CC + k0 + lc_);
    }
#pragma unroll
    for (int q = 0; q < 2; ++q) {      // B: 128 rows x 8 chunks = 1024
      int r = q * 64 + r_;
      async_copy16(Bs + (q * 512 + tid) * 8, Bt + (size_t)(brow0 + r) * CC + k0 + lc_);
    }
  };
  auto compute = [&](const f16* As, const f16* Bs) {
#pragma unroll
    for (int kk = 0; kk < 2; ++kk) {
      half8 af[4], bf[4];
#pragma unroll
      for (int mi = 0; mi < 4; ++mi) af[mi] = ld_swz(As, wr * 64 + mi * 16 + l15, kk * 4 + g);
#pragma unroll
      for (int ni = 0; ni < 4; ++ni) bf[ni] = ld_swz(Bs, wc * 64 + ni * 16 + l15, kk * 4 + g);
#pragma unroll
      for (int mi = 0; mi < 4; ++mi)
#pragma unroll
        for (int ni = 0; ni < 4; ++ni)
          acc[mi][ni] = __builtin_amdgcn_mfma_f32_16x16x32_f16(af[mi], bf[ni], acc[mi][ni], 0, 0, 0);
    }
  };

  const int nt = CC / 64;  // 12
  stage(SMEM, SMEM + 16384, 0);
#pragma unroll 1
  for (int t = 0; t < nt; ++t) {
    f16* cAs = (t & 1) ? SMEM + 24576 : SMEM;
    f16* cBs = (t & 1) ? SMEM + 40960 : SMEM + 16384;
    f16* nAs = (t & 1) ? SMEM : SMEM + 24576;
    f16* nBs = (t & 1) ? SMEM + 16384 : SMEM + 40960;
    if (t + 1 < nt) {
      stage(nAs, nBs, (t + 1) * 64);
      asm volatile("s_waitcnt vmcnt(6)" ::: "memory");
    } else {
      asm volatile("s_waitcnt vmcnt(0)" ::: "memory");
    }
    __builtin_amdgcn_s_barrier();
    __builtin_amdgcn_sched_barrier(0);
    compute(cAs, cBs);
    __builtin_amdgcn_s_barrier();
  }
}

// QKV GEMM: x_h [9232][768] * w_t [2304][768]^T -> q,k [B,H,N,D], v^T [B,H,D,VTLD]
// 256x128 tile; epilogue: acc -> LDS bounce (padded) -> coalesced half8 stores.
__global__ __launch_bounds__(512, 2)
void gemm_qkv(const f16* __restrict__ A, const f16* __restrict__ Bt,
              f16* __restrict__ qb, f16* __restrict__ kb, f16* __restrict__ vt) {
  __shared__ __align__(16) f16 SMEM[49152];   // 96 KB dbuf; epilogue aliases it
  floatx4 acc[4][4] = {};
  const int nwg = 18 * 37;
  const int wgid = xcd_swizzle(blockIdx.y * gridDim.x + blockIdx.x, nwg);
  const int m0 = (wgid / 18) * 256, n0 = (wgid % 18) * 128;
  gemm_mainloop(A, Bt, m0, n0, MM - 1, SMEM, acc, threadIdx.x);
  const int tid = threadIdx.x, lane = tid & 63, wid = tid >> 6;
  const int wr = wid >> 1, wc = wid & 1, l15 = lane & 15, g = lane >> 4;
  const int t = n0 / CC;                 // 0=q, 1=k, 2=v (uniform per block)
  const int h0 = (n0 - t * CC) >> 6;
  // (mainloop ended with s_barrier; SMEM free to reuse)
  if (t < 2) {
    // SMEM[m][n3], m 0..255, stride CLD (34816 f16 <= 49152)
#pragma unroll
    for (int mi = 0; mi < 4; ++mi)
#pragma unroll
      for (int ni = 0; ni < 4; ++ni)
#pragma unroll
        for (int r = 0; r < 4; ++r)
          SMEM[(wr * 64 + mi * 16 + 4 * g + r) * CLD + wc * 64 + ni * 16 + l15] =
              (f16)acc[mi][ni][r];
    __syncthreads();
    f16* dst = (t == 0) ? qb : kb;
#pragma unroll
    for (int p = 0; p < 8; ++p) {
      int c = p * 512 + tid;             // 4096 chunks of 8 f16
      int ml = c >> 4, n3c = (c & 15) << 3;
      int mg = m0 + ml;
      if (mg < MM) {
        int b = mg / NN, n = mg - b * NN;
        int h = h0 + (n3c >> 6), d0 = n3c & 63;
        half8 v = *(const half8*)(SMEM + ml * CLD + n3c);
        *(half8*)(dst + ((size_t)(b * HH + h) * NN + n) * DD + d0) = v;
      }
    }
  } else {
    // SMEM[n3][m] transposed, n3 0..127, stride TLD (33792 f16 <= 49152)
#pragma unroll
    for (int mi = 0; mi < 4; ++mi)
#pragma unroll
      for (int ni = 0; ni < 4; ++ni)
#pragma unroll
        for (int r = 0; r < 4; ++r)
          SMEM[(wc * 64 + ni * 16 + l15) * TLD + wr * 64 + mi * 16 + 4 * g + r] =
              (f16)acc[mi][ni][r];
    __syncthreads();
#pragma unroll
    for (int p = 0; p < 8; ++p) {
      int c = p * 512 + tid;             // 128 n3 x 32 m-chunks = 4096
      int n3 = c >> 5, mc = (c & 31) << 3;
      int mg = m0 + mc;
      int h = h0 + (n3 >> 6), d = n3 & 63;
      half8 v = *(const half8*)(SMEM + n3 * TLD + mc);
      int b0 = mg / NN;
      if (mg + 7 < MM && (mg + 7) / NN == b0) {
        *(half8*)(vt + ((size_t)(b0 * HH + h) * DD + d) * VTLD + (mg - b0 * NN)) = v;
      } else {
#pragma unroll
        for (int e = 0; e < 8; ++e) {
          int m2 = mg + e;
          if (m2 < MM) {
            int b = m2 / NN;
            vt[((size_t)(b * HH + h) * DD + d) * VTLD + (m2 - b * NN)] = v[e];
          }
        }
      }
    }
  }
}

// Proj GEMM: aout [9232][768] * pw_t [768][768]^T + bias -> out f32
__global__ __launch_bounds__(512, 2)
void gemm_proj(const f16* __restrict__ A, const f16* __restrict__ Bt,
               const float* __restrict__ bias, float* __restrict__ out) {
  __shared__ __align__(16) f16 SMEM[49152];
  floatx4 acc[4][4] = {};
  const int nwg = 6 * 37;
  const int wgid = xcd_swizzle(blockIdx.y * gridDim.x + blockIdx.x, nwg);
  const int m0 = (wgid / 6) * 256, n0 = (wgid % 6) * 128;
  gemm_mainloop(A, Bt, m0, n0, MM - 1, SMEM, acc, threadIdx.x);
  const int lane = threadIdx.x & 63, wid = threadIdx.x >> 6;
  const int wr = wid >> 1, wc = wid & 1, l15 = lane & 15, g = lane >> 4;
#pragma unroll
  for (int mi = 0; mi < 4; ++mi)
#pragma unroll
    for (int ni = 0; ni < 4; ++ni)
#pragma unroll
      for (int r = 0; r < 4; ++r) {
        int m = m0 + wr * 64 + mi * 16 + 4 * g + r;
        if (m >= MM) continue;
        int n = n0 + wc * 64 + ni * 16 + l15;
        out[(size_t)m * CC + n] = acc[mi][ni][r] + bias[n];
      }
}

// ---------------------------------------------------------------------------
// Flash attention, swapped-operand form, counted-vmcnt pipeline.
// grid=960 blocks remapped so each XCD owns a contiguous (h-major) chunk.
// 8 waves x 16 q-rows (512 threads), 2 blocks/CU -> 4 waves/SIMD resident
// while the per-CU (b,h) window stays at 2 (L2-safe; r6 showed 3 thrashes).
// S^T = mfma16x16x32(K,Q): lane holds S[q=l15][j=4g+r] == B-frag of 16x16x16
// -> PV with zero P movement. Defer-rescale (T13) with __any-gated local-max
// test, tree max, hoisted tail. V path = r10 form (r11's interleaved-V
// halved bank conflicts but 4x'd V-stage VMEM ops: 55.5->62us, reverted).
// VMEM per tile: [mask(t+1): 4][stage(t+1): 2] -> vmcnt(4) retires exactly
// mask(t)+stage(t), each covered by a full tile of compute.
// ---------------------------------------------------------------------------
__global__ __launch_bounds__(512, 4)
void attn_kernel(const f16* __restrict__ qb, const f16* __restrict__ kb,
                 const f16* __restrict__ vt, const float* __restrict__ Mb,
                 f16* __restrict__ aout) {
  __shared__ f16 Ks[2][64 * 64];   // [j][d] swizzled
  __shared__ f16 Vs[2][64 * 64];   // [d][j] swizzled
  const int D0 = (blockIdx.z * gridDim.y + blockIdx.y) * gridDim.x + blockIdx.x;
  const int wgid = xcd_swizzle(D0, 5 * HH * Bb);   // 960 % 8 == 0
  const int it = wgid % 5;
  const int rem = wgid / 5;
  const int b = rem % Bb, h = rem / Bb;
  const int tid = threadIdx.x, lane = tid & 63, wid = tid >> 6;  // wid 0..7
  const int l15 = lane & 15, g = lane >> 4;
  const size_t bh = (size_t)b * HH + h;
  const f16* qbh = qb + bh * NN * DD;
  const f16* kbh = kb + bh * NN * DD;
  const f16* vbh = vt + bh * DD * VTLD;
  const float* Mh = Mb + (size_t)h * NN * MLD;
  const int row0w = it * 128 + wid * 16;

  // Q B-fragments (held whole kernel): lane holds Q[q=l15][kk*32+g*8 ..+8]
  half8 qB0, qB1;
  {
    int qr = row0w + l15; if (qr > NN - 1) qr = NN - 1;
    const f16* qp = qbh + (size_t)qr * DD + g * 8;
    qB0 = *(const half8*)qp;
    qB1 = *(const half8*)(qp + 32);
  }
  // clamped mask row base
  const float* Mrow;
  {
    int r0 = row0w + l15; if (r0 > NN - 1) r0 = NN - 1;
    Mrow = Mh + (size_t)r0 * MLD + 4 * g;
  }

  floatx4 acc[4] = {};                    // O^T: lane holds O[q=l15][d=dt*16+4g+r]
  float lsum = 0.f;
  float mrun = -3e38f;

  // 512 threads stage a full 64x64 tile in one pass: tid = row*8 + chunk
  const int sr_ = tid >> 3, scp_ = tid & 7;
  const int slc_ = (scp_ ^ (sr_ & 7)) << 3;   // pre-swizzled global col offset
  auto stage = [&](f16* Kd, f16* Vd, int j0) {
    int j = j0 + sr_; if (j > NN - 1) j = NN - 1;
    async_copy16(Kd + tid * 8, kbh + (size_t)j * DD + slc_);
    async_copy16(Vd + tid * 8, vbh + (size_t)sr_ * VTLD + j0 + slc_);
  };
  auto ldmask = [&](floatx4 m4[4], int j0) {
#pragma unroll
    for (int jt = 0; jt < 4; ++jt)
      m4[jt] = *(const floatx4*)(Mrow + j0 + jt * 16);
  };
  auto compute = [&](const f16* Kc, const f16* Vc, floatx4 m4[4], int j0) {
    // S^T = K Q^T : sf[jt][r] = S[q=l15][j0 + jt*16 + 4g + r]
    floatx4 sf[4];
#pragma unroll
    for (int jt = 0; jt < 4; ++jt) {
      half8 ka0 = ld_swz(Kc, jt * 16 + l15, g);
      half8 ka1 = ld_swz(Kc, jt * 16 + l15, 4 + g);
      floatx4 z = {0.f, 0.f, 0.f, 0.f};
      z = __builtin_amdgcn_mfma_f32_16x16x32_f16(ka0, qB0, z, 0, 0, 0);
      z = __builtin_amdgcn_mfma_f32_16x16x32_f16(ka1, qB1, z, 0, 0, 0);
      sf[jt] = z;
    }
    // apply mask
#pragma unroll
    for (int jt = 0; jt < 4; ++jt)
#pragma unroll
      for (int r = 0; r < 4; ++r) sf[jt][r] *= m4[jt][r];
    // tail columns -> -inf (wave-uniform branch; taken only on last tile)
    if (j0 + 64 > NN) {
#pragma unroll
      for (int jt = 0; jt < 4; ++jt)
#pragma unroll
        for (int r = 0; r < 4; ++r)
          if (j0 + jt * 16 + 4 * g + r >= NN) sf[jt][r] = -3e38f;
    }
    // balanced-tree local max; cross-lane reduce+rescale only when needed
    float pj[4];
#pragma unroll
    for (int jt = 0; jt < 4; ++jt)
      pj[jt] = fmaxf(fmaxf(sf[jt][0], sf[jt][1]), fmaxf(sf[jt][2], sf[jt][3]));
    float pmax_loc = fmaxf(fmaxf(pj[0], pj[1]), fmaxf(pj[2], pj[3]));
    if (__any(pmax_loc - mrun > 8.f)) {
      float pmax = fmaxf(pmax_loc, __shfl_xor(pmax_loc, 16));
      pmax = fmaxf(pmax, __shfl_xor(pmax, 32));
      float mnew = fmaxf(mrun, pmax);
      float fac = __builtin_amdgcn_exp2f(mrun - mnew);
      mrun = mnew;
      lsum *= fac;
#pragma unroll
      for (int dt = 0; dt < 4; ++dt)
#pragma unroll
        for (int r = 0; r < 4; ++r) acc[dt][r] *= fac;
    }
    half4 pB[4];
    float lsj[4];
#pragma unroll
    for (int jt = 0; jt < 4; ++jt) {
      half4 pb;
      float p0 = __builtin_amdgcn_exp2f(sf[jt][0] - mrun);
      float p1 = __builtin_amdgcn_exp2f(sf[jt][1] - mrun);
      float p2 = __builtin_amdgcn_exp2f(sf[jt][2] - mrun);
      float p3 = __builtin_amdgcn_exp2f(sf[jt][3] - mrun);
      pb[0] = (f16)p0; pb[1] = (f16)p1; pb[2] = (f16)p2; pb[3] = (f16)p3;
      lsj[jt] = (p0 + p1) + (p2 + p3);
      pB[jt] = pb;
    }
    lsum += (lsj[0] + lsj[1]) + (lsj[2] + lsj[3]);
    // O^T += V^T P^T  (16x16x16: A-frag k=(l>>4)*4+e matches lane-local P)
#pragma unroll
    for (int dt = 0; dt < 4; ++dt)
#pragma unroll
      for (int jt = 0; jt < 4; ++jt) {
        int c16 = (jt * 2 + (g >> 1)) ^ (l15 & 7);   // swizzled 16B chunk
        half4 va = *(const half4*)(Vc + (dt * 16 + l15) * 64 + (c16 << 3) + (g & 1) * 4);
        acc[dt] = __builtin_amdgcn_mfma_f32_16x16x16f16(va, pB[jt], acc[dt], 0, 0, 0);
      }
  };

  floatx4 m4A[4], m4B[4];
  stage(Ks[0], Vs[0], 0);   // 2 global_load_lds
  ldmask(m4A, 0);           // 4 loads

  // 10 tiles, hand-unrolled x2 (even tile -> buf0/m4A, odd tile -> buf1/m4B)
#pragma unroll 1
  for (int t = 0; t < 10; t += 2) {
    // ---- even tile t ----
    ldmask(m4B, (t + 1) * 64);
    asm volatile("s_waitcnt vmcnt(4)" ::: "memory");
    __builtin_amdgcn_s_barrier();
    __builtin_amdgcn_sched_barrier(0);
    stage(Ks[1], Vs[1], (t + 1) * 64);
    compute(Ks[0], Vs[0], m4A, t * 64);
    // ---- odd tile t+1 ----
    const int j2 = (t + 2 < 10) ? (t + 2) * 64 : 0;   // dummy reload on tail
    ldmask(m4A, j2);
    asm volatile("s_waitcnt vmcnt(4)" ::: "memory");
    __builtin_amdgcn_s_barrier();
    __builtin_amdgcn_sched_barrier(0);
    stage(Ks[0], Vs[0], j2);
    compute(Ks[1], Vs[1], m4B, (t + 1) * 64);
  }

  // epilogue: reduce lsum across g-groups, normalize, store [b][n][h][d] f16
  {
    float v = lsum;
    v += __shfl_xor(v, 16);
    v += __shfl_xor(v, 32);
    float linv = 1.f / v;
    int n = row0w + l15;
    if (n < NN) {
#pragma unroll
      for (int dt = 0; dt < 4; ++dt) {
        half4 o;
#pragma unroll
        for (int r = 0; r < 4; ++r) o[r] = (f16)(acc[dt][r] * linv);
        *(half4*)(aout + ((size_t)(b * NN + n)) * CC + h * DD + dt * 16 + 4 * g) = o;
      }
    }
  }
}

// ---------------------------------------------------------------------------
extern "C" void kernel_launch(void* const* d_in, const int* in_sizes, int n_in,
                              void* d_out, int out_size, void* d_ws, size_t ws_size,
                              hipStream_t stream) {
  const float* x    = (const float*)d_in[0];
  const float* qkvw = (const float*)d_in[1];
  const float* pw   = (const float*)d_in[2];
  const float* pb   = (const float*)d_in[3];
  const float* ai   = (const float*)d_in[4];
  const float* mw   = (const float*)d_in[5];
  const float* nrm  = (const float*)d_in[6];
  const int*   ci   = (const int*)d_in[7];
  float* out = (float*)d_out;

  char* wsb = (char*)d_ws;
  size_t off = 0;
  auto alloc = [&](size_t bytes) {
    char* p = wsb + off;
    off += (bytes + 255) & ~(size_t)255;
    return p;
  };
  f16*   x_h  = (f16*)alloc((size_t)MM * CC * 2);        // also reused as aout
  f16*   w_t  = (f16*)alloc((size_t)3 * CC * CC * 2);
  f16*   pw_t = (f16*)alloc((size_t)CC * CC * 2);
  float* Mb   = (float*)alloc((size_t)HH * NN * MLD * 4 + 1024);
  f16*   qb   = (f16*)alloc((size_t)Bb * HH * NN * DD * 2);
  f16*   kb   = (f16*)alloc((size_t)Bb * HH * NN * DD * 2);
  f16*   vt   = (f16*)alloc((size_t)Bb * HH * DD * VTLD * 2);
  (void)alloc(4096);  // tail pad: V^T tail-tile staging reads a few chunks past end
  f16* aout = x_h;    // x_h dead after gemm_qkv; alias to save workspace

  prep_kernel<<<16152, 256, 0, stream>>>(x, qkvw, pw, ai, mw, nrm, ci,
                                         x_h, w_t, pw_t, Mb);
  gemm_qkv<<<dim3(18, 37), 512, 0, stream>>>(x_h, w_t, qb, kb, vt);
  attn_kernel<<<dim3(5, HH, Bb), 512, 0, stream>>>(qb, kb, vt, Mb, aout);
  gemm_proj<<<dim3(6, 37), 512, 0, stream>>>(aout, pw_t, pb, out);
}